// Round 2
// baseline (444.267 us; speedup 1.0000x reference)
//
#include <hip/hip_runtime.h>

#define WINDOW 128
#define H 32
#define O2 256
#define LFRAMES 65536
#define WU 32

// stage1: 96 output frames per block, 128 staged (32 warmup)
#define F1 96
#define S1 128
// stage2: 64 output frames per block, 96 staged
#define F2 64
#define S2 96

__device__ __forceinline__ float selu_f(float x) {
    const float scale = 1.0507009873554805f;
    const float alpha = 1.6732632423543772f;
    return scale * (x > 0.0f ? x : alpha * (expf(x) - 1.0f));
}

// ---------------------------------------------------------------------------
// prep: Wcat[o][k] = k<64 ? (k odd ? -c2i[o][k/2] : c2r[o][k/2]) : d2[o][k-64]
// ---------------------------------------------------------------------------
__global__ void prep_wcat(const float* __restrict__ c2r, const float* __restrict__ c2i,
                          const float* __restrict__ d2, float* __restrict__ wcat)
{
    int idx = blockIdx.x * 256 + threadIdx.x;
    if (idx >= O2 * 96) return;
    int o = idx / 96, k = idx % 96;
    float v;
    if (k < 64) v = (k & 1) ? -c2i[o * H + (k >> 1)] : c2r[o * H + (k >> 1)];
    else        v = d2[o * H + (k - 64)];
    wcat[idx] = v;
}

// ---------------------------------------------------------------------------
// Stage 1: x -> y2 (post-MLP activations, L x 32) and u2 (B2 @ y2, L x 64)
// ---------------------------------------------------------------------------
__global__ __launch_bounds__(256, 2)
void lru_stage1(const float* __restrict__ x,
                const float* __restrict__ b1r, const float* __restrict__ b1i,
                const float* __restrict__ nu1, const float* __restrict__ th1,
                const float* __restrict__ c1r, const float* __restrict__ c1i,
                const float* __restrict__ d1,
                const float* __restrict__ mlp_w, const float* __restrict__ mlp_b,
                const float* __restrict__ b2r, const float* __restrict__ b2i,
                float* __restrict__ y2ws, float* __restrict__ u2ws)
{
    // LDS layout (floats), 18784 floats = 75136 B -> 2 blocks/CU:
    //  [0,8448)      P [128][66]  u1 re/im interleaved      (phase2w -> conv)
    //    overlay:    zbuf [96][32] @0, y2l [96][32] @3072   (phase4 -> 6)
    //  [8448,11616)  d1x [96][33]
    //  [11616,17760) h1 [96][64]
    //    overlay:    scratch [8][128] @11616               (phase2 combine)
    //  [17760,18784) lam1p [32][64]
    __shared__ float smem[18784];
    float* P       = smem;
    float* zbuf    = smem;
    float* y2l     = smem + 3072;
    float* d1x     = smem + 8448;
    float* h1      = smem + 11616;
    float* scratch = smem + 11616;
    float* lam1p   = smem + 17760;

    const int tid = threadIdx.x;
    const int bid = blockIdx.x;
    const int t0 = bid * F1;
    const int frame0 = t0 - WU;

    // lambda powers with gamma folded in: lam1p[j][2c..] = gamma * lam^j
    if (tid < H) {
        float enu = expf(nu1[tid]);
        float mag = expf(-enu);
        float ang = expf(th1[tid]);
        float lr = mag * cosf(ang), li = mag * sinf(ang);
        float g = sqrtf(fmaxf(1.0f - mag * mag, 0.0f));
        float pr = g, pi = 0.0f;
        for (int j = 0; j < WU; ++j) {
            lam1p[j * 64 + 2 * tid]     = pr;
            lam1p[j * 64 + 2 * tid + 1] = pi;
            float npr = pr * lr - pi * li;
            float npi = pr * li + pi * lr;
            pr = npr; pi = npi;
        }
    }

    // phase 1: x -> registers. lane owns (frame f, half kh): 64 floats.
    const int f = tid & 127;
    const int kh = __builtin_amdgcn_readfirstlane(tid >> 7);  // wave-uniform
    float4 xr[16];
    {
        int gf = frame0 + f;
        if (gf >= 0 && gf < LFRAMES) {
            const float* xp = x + (size_t)gf * WINDOW + kh * 64;
            #pragma unroll
            for (int q = 0; q < 16; ++q) xr[q] = *(const float4*)(xp + 4 * q);
        } else {
            #pragma unroll
            for (int q = 0; q < 16; ++q) xr[q] = make_float4(0.f, 0.f, 0.f, 0.f);
        }
    }

    // phase 2: rows 0..31 = b1r, 32..63 = b1i, 64..95 = d1. 12 groups of 8 rows.
    // Weights via wave-uniform s_loads; x from registers; combine kh halves via LDS.
    #pragma unroll 1
    for (int g = 0; g < 12; ++g) {
        const int reg = g >> 2;
        const float* wbase = (reg == 0) ? b1r : ((reg == 1) ? b1i : d1);
        const float* wrows[8];
        #pragma unroll
        for (int m = 0; m < 8; ++m)
            wrows[m] = wbase + (((g & 3) * 8 + m) * WINDOW) + kh * 64;

        float acc[8];
        #pragma unroll
        for (int m = 0; m < 8; ++m) acc[m] = 0.f;

        #pragma unroll
        for (int k4 = 0; k4 < 16; ++k4) {
            float4 xv = xr[k4];
            #pragma unroll
            for (int m = 0; m < 8; ++m) {
                float4 wv = *(const float4*)(wrows[m] + 4 * k4);
                acc[m] = fmaf(wv.x, xv.x, acc[m]);
                acc[m] = fmaf(wv.y, xv.y, acc[m]);
                acc[m] = fmaf(wv.z, xv.z, acc[m]);
                acc[m] = fmaf(wv.w, xv.w, acc[m]);
            }
        }

        __syncthreads();   // scratch free (also orders staging at g=0)
        if (kh == 1) {
            #pragma unroll
            for (int m = 0; m < 8; ++m) scratch[m * 128 + f] = acc[m];
        }
        __syncthreads();
        if (kh == 0) {
            #pragma unroll
            for (int m = 0; m < 8; ++m) {
                float v = acc[m] + scratch[m * 128 + f];
                int r = (g & 3) * 8 + m;   // row within matrix
                if (reg == 0)      P[f * 66 + 2 * r] = v;
                else if (reg == 1) P[f * 66 + 2 * r + 1] = v;
                else if (f >= WU)  d1x[(f - WU) * 33 + r] = v;
            }
        }
    }
    __syncthreads();

    // phase 3: conv (32-tap truncated window, exact to ~1e-14) + short scan.
    {
        int c = tid & 31;
        int fg = tid >> 5;
        float enu = expf(nu1[c]);
        float mag = expf(-enu);
        float ang = expf(th1[c]);
        float lr = mag * cosf(ang), li = mag * sinf(ang);
        float g = sqrtf(fmaxf(1.0f - mag * mag, 0.0f));
        int f0 = WU + fg * 12;
        float hre = 0.f, him = 0.f;
        for (int j = 0; j < WU; ++j) {
            float2 lp = *(const float2*)(lam1p + j * 64 + 2 * c);
            float2 u  = *(const float2*)(P + (f0 - j) * 66 + 2 * c);
            hre = fmaf(lp.x, u.x, hre); hre = fmaf(-lp.y, u.y, hre);
            him = fmaf(lp.x, u.y, him); him = fmaf(lp.y, u.x, him);
        }
        h1[(fg * 12) * 64 + 2 * c]     = hre;
        h1[(fg * 12) * 64 + 2 * c + 1] = him;
        for (int s = 1; s < 12; ++s) {
            float2 u = *(const float2*)(P + (f0 + s) * 66 + 2 * c);
            float nre = lr * hre - li * him + g * u.x;
            float nim = lr * him + li * hre + g * u.y;
            hre = nre; him = nim;
            h1[(fg * 12 + s) * 64 + 2 * c]     = hre;
            h1[(fg * 12 + s) * 64 + 2 * c + 1] = him;
        }
    }
    __syncthreads();

    // phase 4: y1 = Re(C1 h1) + D1x, selu -> zbuf (overlays P; P is dead)
    for (int p = 0; p < 12; ++p) {
        int c = tid & 31;
        int fi = (tid >> 5) + 8 * p;
        float y = d1x[fi * 33 + c];
        const float4* crp = (const float4*)(c1r + c * H);
        const float4* cip = (const float4*)(c1i + c * H);
        const float4* hp  = (const float4*)(h1 + fi * 64);
        #pragma unroll
        for (int q = 0; q < 8; ++q) {
            float4 cr = crp[q], ci = cip[q];
            float4 ha = hp[2 * q], hb = hp[2 * q + 1];
            y = fmaf(cr.x, ha.x, y); y = fmaf(-ci.x, ha.y, y);
            y = fmaf(cr.y, ha.z, y); y = fmaf(-ci.y, ha.w, y);
            y = fmaf(cr.z, hb.x, y); y = fmaf(-ci.z, hb.y, y);
            y = fmaf(cr.w, hb.z, y); y = fmaf(-ci.w, hb.w, y);
        }
        zbuf[fi * 32 + c] = selu_f(y);
    }
    __syncthreads();

    // phase 5: MLP + selu -> y2l and y2ws
    for (int p = 0; p < 12; ++p) {
        int c = tid & 31;
        int fi = (tid >> 5) + 8 * p;
        float m = mlp_b[c];
        #pragma unroll 4
        for (int h = 0; h < H; ++h)
            m = fmaf(zbuf[fi * 32 + h], mlp_w[h * 32 + c], m);
        float v = selu_f(m);
        y2l[fi * 32 + c] = v;
        if (t0 + fi < LFRAMES) y2ws[(size_t)(t0 + fi) * H + c] = v;
    }
    __syncthreads();

    // phase 6: u2 = B2 @ y2
    for (int p = 0; p < 12; ++p) {
        int c = tid & 31;
        int fi = (tid >> 5) + 8 * p;
        float re = 0.f, im = 0.f;
        const float4* brp = (const float4*)(b2r + c * H);
        const float4* bip = (const float4*)(b2i + c * H);
        const float4* yp  = (const float4*)(y2l + fi * 32);
        #pragma unroll
        for (int q = 0; q < 8; ++q) {
            float4 br = brp[q], bi = bip[q], yv = yp[q];
            re = fmaf(br.x, yv.x, re); re = fmaf(br.y, yv.y, re);
            re = fmaf(br.z, yv.z, re); re = fmaf(br.w, yv.w, re);
            im = fmaf(bi.x, yv.x, im); im = fmaf(bi.y, yv.y, im);
            im = fmaf(bi.z, yv.z, im); im = fmaf(bi.w, yv.w, im);
        }
        if (t0 + fi < LFRAMES) {
            float2 o; o.x = re; o.y = im;
            *(float2*)(u2ws + (size_t)(t0 + fi) * 2 * H + 2 * c) = o;
        }
    }
}

// ---------------------------------------------------------------------------
// Stage 2: y2/u2 -> out = Wcat @ [h2re; h2im; y2]
// ---------------------------------------------------------------------------
__global__ __launch_bounds__(256, 2)
void lru_stage2(const float* __restrict__ y2ws, const float* __restrict__ u2ws,
                const float* __restrict__ nu2, const float* __restrict__ th2,
                const float* __restrict__ wcat,
                float* __restrict__ out)
{
    // LDS (floats): y2s [96][33] @0 | u2s [96][66] @3168 | h2 [64][67] @9504
    //               | lam2p [32][64] @13792   -> 15840 floats = 63360 B
    __shared__ float smem[15840];
    float* y2s   = smem;
    float* u2s   = smem + 3168;
    float* h2    = smem + 9504;
    float* lam2p = smem + 13792;

    const int tid = threadIdx.x;
    const int bid = blockIdx.x;
    const int t0 = bid * F2;
    const int frame0 = t0 - WU;

    if (tid < H) {
        float enu = expf(nu2[tid]);
        float mag = expf(-enu);
        float ang = expf(th2[tid]);
        float lr = mag * cosf(ang), li = mag * sinf(ang);
        float g = sqrtf(fmaxf(1.0f - mag * mag, 0.0f));
        float pr = g, pi = 0.0f;
        for (int j = 0; j < WU; ++j) {
            lam2p[j * 64 + 2 * tid]     = pr;
            lam2p[j * 64 + 2 * tid + 1] = pi;
            float npr = pr * lr - pi * li;
            float npi = pr * li + pi * lr;
            pr = npr; pi = npi;
        }
    }

    // stage y2 / u2
    for (int p = 0; p < 12; ++p) {
        int idx = tid + 256 * p;
        int fr = idx >> 5, c = idx & 31;
        int gf = frame0 + fr;
        y2s[fr * 33 + c] = (gf >= 0) ? y2ws[(size_t)gf * H + c] : 0.f;
    }
    for (int p = 0; p < 12; ++p) {
        int idx = tid + 256 * p;
        int fr = idx >> 5, j = idx & 31;
        int gf = frame0 + fr;
        float2 v = make_float2(0.f, 0.f);
        if (gf >= 0) v = *(const float2*)(u2ws + (size_t)gf * 2 * H + 2 * j);
        *(float2*)(u2s + fr * 66 + 2 * j) = v;
    }
    __syncthreads();

    // conv2 + scan -> h2 [64][67], (re, +im) interleaved
    {
        int c = tid & 31;
        int fg = tid >> 5;
        float enu = expf(nu2[c]);
        float mag = expf(-enu);
        float ang = expf(th2[c]);
        float lr = mag * cosf(ang), li = mag * sinf(ang);
        float g = sqrtf(fmaxf(1.0f - mag * mag, 0.0f));
        int f0 = WU + fg * 8;
        float hre = 0.f, him = 0.f;
        for (int j = 0; j < WU; ++j) {
            float2 lp = *(const float2*)(lam2p + j * 64 + 2 * c);
            float2 u  = *(const float2*)(u2s + (f0 - j) * 66 + 2 * c);
            hre = fmaf(lp.x, u.x, hre); hre = fmaf(-lp.y, u.y, hre);
            him = fmaf(lp.x, u.y, him); him = fmaf(lp.y, u.x, him);
        }
        h2[(fg * 8) * 67 + 2 * c]     = hre;
        h2[(fg * 8) * 67 + 2 * c + 1] = him;
        for (int s = 1; s < 8; ++s) {
            float2 u = *(const float2*)(u2s + (f0 + s) * 66 + 2 * c);
            float nre = lr * hre - li * him + g * u.x;
            float nim = lr * him + li * hre + g * u.y;
            hre = nre; him = nim;
            h2[(fg * 8 + s) * 67 + 2 * c]     = hre;
            h2[(fg * 8 + s) * 67 + 2 * c + 1] = him;
        }
    }
    __syncthreads();

    // output GEMM: lane owns frame fl; wave owns 64 output rows; weights via s_load.
    {
        const int fl = tid & 63;
        const int wid = __builtin_amdgcn_readfirstlane(tid >> 6);
        const float* h2row = h2 + fl * 67;
        const float* y2row = y2s + (fl + WU) * 33;
        #pragma unroll 1
        for (int oc = 0; oc < 8; ++oc) {
            const int obase = wid * 64 + oc * 8;
            const float* wp = wcat + (size_t)obase * 96;
            float acc[8];
            #pragma unroll
            for (int m = 0; m < 8; ++m) acc[m] = 0.f;

            #pragma unroll 4
            for (int k4 = 0; k4 < 16; ++k4) {       // h2 part: k = 0..63
                float b0 = h2row[4 * k4];
                float b1 = h2row[4 * k4 + 1];
                float b2 = h2row[4 * k4 + 2];
                float b3 = h2row[4 * k4 + 3];
                #pragma unroll
                for (int m = 0; m < 8; ++m) {
                    float4 w = *(const float4*)(wp + m * 96 + 4 * k4);
                    acc[m] = fmaf(w.x, b0, acc[m]);
                    acc[m] = fmaf(w.y, b1, acc[m]);
                    acc[m] = fmaf(w.z, b2, acc[m]);
                    acc[m] = fmaf(w.w, b3, acc[m]);
                }
            }
            #pragma unroll 4
            for (int k4 = 0; k4 < 8; ++k4) {        // y2 part: k = 64..95
                float b0 = y2row[4 * k4];
                float b1 = y2row[4 * k4 + 1];
                float b2 = y2row[4 * k4 + 2];
                float b3 = y2row[4 * k4 + 3];
                #pragma unroll
                for (int m = 0; m < 8; ++m) {
                    float4 w = *(const float4*)(wp + m * 96 + 64 + 4 * k4);
                    acc[m] = fmaf(w.x, b0, acc[m]);
                    acc[m] = fmaf(w.y, b1, acc[m]);
                    acc[m] = fmaf(w.z, b2, acc[m]);
                    acc[m] = fmaf(w.w, b3, acc[m]);
                }
            }
            #pragma unroll
            for (int m = 0; m < 8; ++m)
                out[(size_t)(obase + m) * LFRAMES + t0 + fl] = acc[m];
        }
    }
}

extern "C" void kernel_launch(void* const* d_in, const int* in_sizes, int n_in,
                              void* d_out, int out_size, void* d_ws, size_t ws_size,
                              hipStream_t stream)
{
    const float* x     = (const float*)d_in[0];
    const float* b1r   = (const float*)d_in[1];
    const float* b1i   = (const float*)d_in[2];
    const float* nu1   = (const float*)d_in[3];
    const float* th1   = (const float*)d_in[4];
    const float* c1r   = (const float*)d_in[5];
    const float* c1i   = (const float*)d_in[6];
    const float* d1    = (const float*)d_in[7];
    const float* mlp_w = (const float*)d_in[8];
    const float* mlp_b = (const float*)d_in[9];
    const float* b2r   = (const float*)d_in[10];
    const float* b2i   = (const float*)d_in[11];
    const float* nu2   = (const float*)d_in[12];
    const float* th2   = (const float*)d_in[13];
    const float* c2r   = (const float*)d_in[14];
    const float* c2i   = (const float*)d_in[15];
    const float* d2    = (const float*)d_in[16];
    float* out = (float*)d_out;

    float* y2ws = (float*)d_ws;                           // L*32 floats
    float* u2ws = y2ws + (size_t)LFRAMES * H;             // L*64 floats
    float* wcat = u2ws + (size_t)LFRAMES * 2 * H;         // 256*96 floats

    prep_wcat<<<dim3((O2 * 96 + 255) / 256), dim3(256), 0, stream>>>(c2r, c2i, d2, wcat);

    dim3 blk(256);
    lru_stage1<<<dim3((LFRAMES + F1 - 1) / F1), blk, 0, stream>>>(
        x, b1r, b1i, nu1, th1, c1r, c1i, d1, mlp_w, mlp_b, b2r, b2i, y2ws, u2ws);
    lru_stage2<<<dim3(LFRAMES / F2), blk, 0, stream>>>(
        y2ws, u2ws, nu2, th2, wcat, out);
}

// Round 3
// 59.829 us; speedup vs baseline: 7.4256x; 7.4256x over previous
//
#include <hip/hip_runtime.h>

#define WINDOW 128
#define H 32
#define O2 256
#define LFRAMES 65536
#define WU 32

// stage1: 256 output frames/block, 288 staged (18 N-tiles), 512 threads
#define S1_FO 256
#define S1_FS 288
// stage2: 64 output frames/block, 96 staged, 256 threads
#define S2_FO 64

using bf16x8 = __attribute__((ext_vector_type(8))) short;
using f32x4  = __attribute__((ext_vector_type(4))) float;
using u16x4  = __attribute__((ext_vector_type(4))) unsigned short;

__device__ __forceinline__ unsigned bf16r(float v) {   // RTNE float->bf16 bits
    unsigned u = __builtin_bit_cast(unsigned, v);
    return (u + 0x7FFFu + ((u >> 16) & 1u)) >> 16;
}
__device__ __forceinline__ float bf2f(unsigned s) {
    return __builtin_bit_cast(float, s << 16);
}
__device__ __forceinline__ float selu_f(float x) {
    const float scale = 1.0507009873554805f;
    const float alpha = 1.6732632423543772f;
    return scale * (x > 0.0f ? x : alpha * (expf(x) - 1.0f));
}
__device__ __forceinline__ bf16x8 cvt8(float4 a, float4 b) {
    bf16x8 r;
    r[0] = (short)bf16r(a.x); r[1] = (short)bf16r(a.y);
    r[2] = (short)bf16r(a.z); r[3] = (short)bf16r(a.w);
    r[4] = (short)bf16r(b.x); r[5] = (short)bf16r(b.y);
    r[6] = (short)bf16r(b.z); r[7] = (short)bf16r(b.w);
    return r;
}

// ---------------- stage1 LDS byte offsets (total 161152 <= 160KiB) ----------
#define OFF_LAM1   0        // [32][64] f32                        (8192)
#define OFF_C1HI   8192     // [32][72] bf16, pitch 144B           (4608)
#define OFF_C1LO   12800
#define OFF_MWHI   17408    // [32][40] bf16, pitch 80B            (2560)
#define OFF_MWLO   19968
#define OFF_B2HI   22528    // [64][40] bf16, pitch 80B            (5120)
#define OFF_B2LO   27648
#define OFF_BIAS   32768    // [32] f32                            (128)
#define OFF_P      32896    // [288][68] bf16, pitch 136B          (39168)
#define OFF_Y1S    32896    // overlay: [256][40] bf16, pitch 80B
#define OFF_D1X    72064    // [256][36] f32, pitch 144B           (36864)
#define OFF_Y2L    72064    // overlay: [256][40] bf16, pitch 80B
#define OFF_W1HI   108928   // [96][136] bf16, pitch 272B          (26112)
#define OFF_W1LO   135040   //                                     (26112)
#define OFF_H1     108928   // overlay: [256][72] bf16, pitch 144B (36864)
#define S1_LDS     161152

// ---------------- stage2 LDS byte offsets (total 47616) ---------------------
#define OFF_LAM2   0        // [32][64] f32    (8192)
#define OFF_U2S    8192     // [96][68] f32, pitch 272B  (26112)
#define OFF_BIMG   34304    // [64][104] bf16, pitch 208B (13312); k0..63=h2, 64..95=y2
#define S2_LDS     47616

// ---------------------------------------------------------------------------
// prep: wcat (256 x 96) bf16 hi/lo. k<64: even->c2r, odd->-c2i; k>=64: d2.
// ---------------------------------------------------------------------------
__global__ void prep_wcat(const float* __restrict__ c2r, const float* __restrict__ c2i,
                          const float* __restrict__ d2,
                          unsigned short* __restrict__ whi, unsigned short* __restrict__ wlo)
{
    int idx = blockIdx.x * 256 + threadIdx.x;
    if (idx >= O2 * 96) return;
    int row = idx / 96, k = idx - row * 96;
    float v;
    if (k < 64) v = (k & 1) ? -c2i[row * H + (k >> 1)] : c2r[row * H + (k >> 1)];
    else        v = d2[row * H + (k - 64)];
    unsigned h = bf16r(v);
    whi[idx] = (unsigned short)h;
    wlo[idx] = (unsigned short)bf16r(v - bf2f(h));
}

// ---------------------------------------------------------------------------
// Stage 1
// ---------------------------------------------------------------------------
__global__ __launch_bounds__(512)
void lru_stage1(const float* __restrict__ x,
                const float* __restrict__ b1r, const float* __restrict__ b1i,
                const float* __restrict__ nu1, const float* __restrict__ th1,
                const float* __restrict__ c1r, const float* __restrict__ c1i,
                const float* __restrict__ d1,
                const float* __restrict__ mlp_w, const float* __restrict__ mlp_b,
                const float* __restrict__ b2r, const float* __restrict__ b2i,
                unsigned short* __restrict__ y2ws, float* __restrict__ u2ws)
{
    __shared__ __align__(16) char smem[S1_LDS];
    const int tid = threadIdx.x;
    const int t0 = blockIdx.x * S1_FO;
    const int frame0 = t0 - WU;
    const int w = tid >> 6, l = tid & 63, l15 = l & 15, lq = l >> 4;

    // ---- phase 0: weight conversion into LDS + lambda table ----
    if (tid < H) {
        float enu = expf(nu1[tid]);
        float mag = expf(-enu);
        float ang = expf(th1[tid]);
        float lr = mag * cosf(ang), li = mag * sinf(ang);
        float g = sqrtf(fmaxf(1.0f - mag * mag, 0.0f));
        float pr = g, pi = 0.0f;
        float* lam = (float*)(smem + OFF_LAM1);
        for (int j = 0; j < WU; ++j) {
            lam[j * 64 + 2 * tid] = pr;
            lam[j * 64 + 2 * tid + 1] = pi;
            float npr = pr * lr - pi * li, npi = pr * li + pi * lr;
            pr = npr; pi = npi;
        }
        ((float*)(smem + OFF_BIAS))[tid] = mlp_b[tid];
    }
    // W1: rows 0..63 interleaved (2c=b1r[c], 2c+1=b1i[c]), 64..95 = d1
    {
        unsigned short* hi = (unsigned short*)(smem + OFF_W1HI);
        unsigned short* lo = (unsigned short*)(smem + OFF_W1LO);
        #pragma unroll
        for (int p = 0; p < 24; ++p) {
            int idx = tid + 512 * p;
            int row = idx >> 7, k = idx & 127;
            float v;
            if (row < 64) v = (row & 1) ? b1i[(row >> 1) * WINDOW + k] : b1r[(row >> 1) * WINDOW + k];
            else          v = d1[(row - 64) * WINDOW + k];
            unsigned h = bf16r(v);
            hi[row * 136 + k] = (unsigned short)h;
            lo[row * 136 + k] = (unsigned short)bf16r(v - bf2f(h));
        }
    }
    // C1cat: [32][64], k even -> c1r, k odd -> -c1i
    {
        unsigned short* hi = (unsigned short*)(smem + OFF_C1HI);
        unsigned short* lo = (unsigned short*)(smem + OFF_C1LO);
        #pragma unroll
        for (int p = 0; p < 4; ++p) {
            int idx = tid + 512 * p;
            int row = idx >> 6, k = idx & 63;
            float v = (k & 1) ? -c1i[row * H + (k >> 1)] : c1r[row * H + (k >> 1)];
            unsigned h = bf16r(v);
            hi[row * 72 + k] = (unsigned short)h;
            lo[row * 72 + k] = (unsigned short)bf16r(v - bf2f(h));
        }
    }
    // mlpw^T: A[o][i] = mlp_w[i*32+o]
    {
        unsigned short* hi = (unsigned short*)(smem + OFF_MWHI);
        unsigned short* lo = (unsigned short*)(smem + OFF_MWLO);
        #pragma unroll
        for (int p = 0; p < 2; ++p) {
            int idx = tid + 512 * p;
            int row = idx >> 5, k = idx & 31;
            float v = mlp_w[k * H + row];
            unsigned h = bf16r(v);
            hi[row * 40 + k] = (unsigned short)h;
            lo[row * 40 + k] = (unsigned short)bf16r(v - bf2f(h));
        }
    }
    // b2cat: rows interleaved (2c=b2r[c], 2c+1=b2i[c]), K=32
    {
        unsigned short* hi = (unsigned short*)(smem + OFF_B2HI);
        unsigned short* lo = (unsigned short*)(smem + OFF_B2LO);
        #pragma unroll
        for (int p = 0; p < 4; ++p) {
            int idx = tid + 512 * p;
            int row = idx >> 5, k = idx & 31;
            float v = (row & 1) ? b2i[(row >> 1) * H + k] : b2r[(row >> 1) * H + k];
            unsigned h = bf16r(v);
            hi[row * 40 + k] = (unsigned short)h;
            lo[row * 40 + k] = (unsigned short)bf16r(v - bf2f(h));
        }
    }
    __syncthreads();

    // ---- GEMM1: U1(96 x 288) = W1 @ X ; A from LDS, B built from global x ----
    f32x4 acc1[3][6];
    #pragma unroll
    for (int ni = 0; ni < 3; ++ni)
        #pragma unroll
        for (int m = 0; m < 6; ++m) acc1[ni][m] = f32x4{0.f, 0.f, 0.f, 0.f};

    #pragma unroll 1
    for (int ks = 0; ks < 4; ++ks) {
        bf16x8 ah[6], al[6];
        #pragma unroll
        for (int m = 0; m < 6; ++m) {
            int ro = (m * 16 + l15) * 272 + ks * 64 + lq * 16;
            ah[m] = *(const bf16x8*)(smem + OFF_W1HI + ro);
            al[m] = *(const bf16x8*)(smem + OFF_W1LO + ro);
        }
        #pragma unroll
        for (int ni = 0; ni < 3; ++ni) {
            int nt = w + ni * 8;
            if (nt < 18) {
                int gf = frame0 + nt * 16 + l15;
                float4 xa{}, xb{};
                if (gf >= 0 && gf < LFRAMES) {
                    const float4* xp = (const float4*)(x + (size_t)gf * WINDOW + ks * 32 + lq * 8);
                    xa = xp[0]; xb = xp[1];
                }
                bf16x8 b = cvt8(xa, xb);
                #pragma unroll
                for (int m = 0; m < 6; ++m) {
                    acc1[ni][m] = __builtin_amdgcn_mfma_f32_16x16x32_bf16(ah[m], b, acc1[ni][m], 0, 0, 0);
                    acc1[ni][m] = __builtin_amdgcn_mfma_f32_16x16x32_bf16(al[m], b, acc1[ni][m], 0, 0, 0);
                }
            }
        }
    }
    // epilogue: rows 0..63 -> P (bf16), rows 64..95 -> d1x (f32, out frames only)
    #pragma unroll
    for (int ni = 0; ni < 3; ++ni) {
        int nt = w + ni * 8;
        if (nt < 18) {
            int fr = nt * 16 + l15;
            #pragma unroll
            for (int m = 0; m < 4; ++m) {
                u16x4 pk;
                #pragma unroll
                for (int j = 0; j < 4; ++j) pk[j] = (unsigned short)bf16r(acc1[ni][m][j]);
                *(u16x4*)(smem + OFF_P + fr * 136 + (m * 16 + lq * 4) * 2) = pk;
            }
            if (fr >= WU) {
                #pragma unroll
                for (int m = 4; m < 6; ++m)
                    *(f32x4*)(smem + OFF_D1X + (fr - WU) * 144 + ((m - 4) * 16 + lq * 4) * 4) = acc1[ni][m];
            }
        }
    }
    __syncthreads();

    // ---- conv1: 32-tap window + 16-step scan -> h1 (bf16) ----
    {
        int c = tid & 31, fg = tid >> 5;
        float enu = expf(nu1[c]);
        float mag = expf(-enu);
        float ang = expf(th1[c]);
        float lr = mag * cosf(ang), li = mag * sinf(ang);
        float g = sqrtf(fmaxf(1.0f - mag * mag, 0.0f));
        const float* lam = (const float*)(smem + OFF_LAM1);
        int o0 = fg * 16;
        float hre = 0.f, him = 0.f;
        for (int j = 0; j < WU; ++j) {
            float2 lp = *(const float2*)(lam + j * 64 + 2 * c);
            unsigned uw = *(const unsigned*)(smem + OFF_P + (o0 + WU - j) * 136 + c * 4);
            float ur = bf2f(uw & 0xFFFFu), ui = bf2f(uw >> 16);
            hre = fmaf(lp.x, ur, hre); hre = fmaf(-lp.y, ui, hre);
            him = fmaf(lp.x, ui, him); him = fmaf(lp.y, ur, him);
        }
        *(unsigned*)(smem + OFF_H1 + o0 * 144 + c * 4) = (bf16r(him) << 16) | bf16r(hre);
        for (int s = 1; s < 16; ++s) {
            unsigned uw = *(const unsigned*)(smem + OFF_P + (o0 + WU + s) * 136 + c * 4);
            float ur = bf2f(uw & 0xFFFFu), ui = bf2f(uw >> 16);
            float nre = lr * hre - li * him + g * ur;
            float nim = lr * him + li * hre + g * ui;
            hre = nre; him = nim;
            *(unsigned*)(smem + OFF_H1 + (o0 + s) * 144 + c * 4) = (bf16r(him) << 16) | bf16r(hre);
        }
    }
    __syncthreads();

    // ---- GEMM2: y1 = C1cat @ h1 + d1x ; selu -> y1s (overlay P) ----
    #pragma unroll 1
    for (int ci = w; ci < 32; ci += 8) {
        int n = ci >> 1, m = ci & 1;
        int fcol = n * 16 + l15;
        f32x4 c = *(const f32x4*)(smem + OFF_D1X + fcol * 144 + (m * 16 + lq * 4) * 4);
        #pragma unroll
        for (int ks = 0; ks < 2; ++ks) {
            int ao = (m * 16 + l15) * 144 + ks * 64 + lq * 16;
            bf16x8 ah = *(const bf16x8*)(smem + OFF_C1HI + ao);
            bf16x8 al = *(const bf16x8*)(smem + OFF_C1LO + ao);
            bf16x8 bb = *(const bf16x8*)(smem + OFF_H1 + fcol * 144 + ks * 64 + lq * 16);
            c = __builtin_amdgcn_mfma_f32_16x16x32_bf16(ah, bb, c, 0, 0, 0);
            c = __builtin_amdgcn_mfma_f32_16x16x32_bf16(al, bb, c, 0, 0, 0);
        }
        u16x4 pk;
        #pragma unroll
        for (int j = 0; j < 4; ++j) pk[j] = (unsigned short)bf16r(selu_f(c[j]));
        *(u16x4*)(smem + OFF_Y1S + fcol * 80 + (m * 16 + lq * 4) * 2) = pk;
    }
    __syncthreads();

    // ---- MLP: y2 = mlpw^T @ y1s + bias ; selu -> y2l (overlay d1x) + y2ws ----
    #pragma unroll 1
    for (int ci = w; ci < 32; ci += 8) {
        int n = ci >> 1, m = ci & 1;
        int fcol = n * 16 + l15;
        f32x4 c = *(const f32x4*)(smem + OFF_BIAS + (m * 16 + lq * 4) * 4);
        {
            int ao = (m * 16 + l15) * 80 + lq * 16;
            bf16x8 ah = *(const bf16x8*)(smem + OFF_MWHI + ao);
            bf16x8 al = *(const bf16x8*)(smem + OFF_MWLO + ao);
            bf16x8 bb = *(const bf16x8*)(smem + OFF_Y1S + fcol * 80 + lq * 16);
            c = __builtin_amdgcn_mfma_f32_16x16x32_bf16(ah, bb, c, 0, 0, 0);
            c = __builtin_amdgcn_mfma_f32_16x16x32_bf16(al, bb, c, 0, 0, 0);
        }
        u16x4 pk;
        #pragma unroll
        for (int j = 0; j < 4; ++j) pk[j] = (unsigned short)bf16r(selu_f(c[j]));
        *(u16x4*)(smem + OFF_Y2L + fcol * 80 + (m * 16 + lq * 4) * 2) = pk;
        *(u16x4*)(y2ws + (size_t)(t0 + fcol) * H + (m * 16 + lq * 4)) = pk;
    }
    __syncthreads();

    // ---- GEMM3: u2 = b2cat @ y2l -> u2ws (f32) ----
    #pragma unroll 1
    for (int ci = w; ci < 64; ci += 8) {
        int n = ci >> 2, m = ci & 3;
        int fcol = n * 16 + l15;
        f32x4 c = f32x4{0.f, 0.f, 0.f, 0.f};
        {
            int ao = (m * 16 + l15) * 80 + lq * 16;
            bf16x8 ah = *(const bf16x8*)(smem + OFF_B2HI + ao);
            bf16x8 al = *(const bf16x8*)(smem + OFF_B2LO + ao);
            bf16x8 bb = *(const bf16x8*)(smem + OFF_Y2L + fcol * 80 + lq * 16);
            c = __builtin_amdgcn_mfma_f32_16x16x32_bf16(ah, bb, c, 0, 0, 0);
            c = __builtin_amdgcn_mfma_f32_16x16x32_bf16(al, bb, c, 0, 0, 0);
        }
        *(f32x4*)(u2ws + (size_t)(t0 + fcol) * 64 + (m * 16 + lq * 4)) = c;
    }
}

// ---------------------------------------------------------------------------
// Stage 2: conv2 + out = Wcat @ [h2; y2]
// ---------------------------------------------------------------------------
__global__ __launch_bounds__(256, 3)
void lru_stage2(const float* __restrict__ u2ws, const unsigned short* __restrict__ y2ws,
                const float* __restrict__ nu2, const float* __restrict__ th2,
                const unsigned short* __restrict__ whi, const unsigned short* __restrict__ wlo,
                float* __restrict__ out)
{
    __shared__ __align__(16) char smem[S2_LDS];
    const int tid = threadIdx.x;
    const int t0 = blockIdx.x * S2_FO;
    const int l = tid & 63, l15 = l & 15, lq = l >> 4;
    const int wid = tid >> 6;

    if (tid < H) {
        float enu = expf(nu2[tid]);
        float mag = expf(-enu);
        float ang = expf(th2[tid]);
        float lr = mag * cosf(ang), li = mag * sinf(ang);
        float g = sqrtf(fmaxf(1.0f - mag * mag, 0.0f));
        float pr = g, pi = 0.0f;
        float* lam = (float*)(smem + OFF_LAM2);
        for (int j = 0; j < WU; ++j) {
            lam[j * 64 + 2 * tid] = pr;
            lam[j * 64 + 2 * tid + 1] = pi;
            float npr = pr * lr - pi * li, npi = pr * li + pi * lr;
            pr = npr; pi = npi;
        }
    }
    // stage u2 (96 frames x 64 f32)
    #pragma unroll
    for (int p = 0; p < 6; ++p) {
        int i = tid + 256 * p;
        int f = i >> 4, q = i & 15;
        int gf = t0 - WU + f;
        f32x4 v = f32x4{0.f, 0.f, 0.f, 0.f};
        if (gf >= 0) v = *(const f32x4*)(u2ws + (size_t)gf * 64 + q * 4);
        *(f32x4*)(smem + OFF_U2S + f * 272 + q * 16) = v;
    }
    // stage y2 (bf16) into Bimg cols 64..95
    {
        int f = tid >> 2, q = tid & 3;
        int gf = t0 + f;
        bf16x8 v = *(const bf16x8*)(y2ws + (size_t)gf * H + q * 8);
        *(bf16x8*)(smem + OFF_BIMG + f * 208 + 128 + q * 16) = v;
    }
    __syncthreads();

    // conv2 -> h2 (bf16) into Bimg cols 0..63
    {
        int c = tid & 31, fg = tid >> 5;
        float enu = expf(nu2[c]);
        float mag = expf(-enu);
        float ang = expf(th2[c]);
        float lr = mag * cosf(ang), li = mag * sinf(ang);
        float g = sqrtf(fmaxf(1.0f - mag * mag, 0.0f));
        const float* lam = (const float*)(smem + OFF_LAM2);
        int o0 = fg * 8;
        float hre = 0.f, him = 0.f;
        for (int j = 0; j < WU; ++j) {
            float2 lp = *(const float2*)(lam + j * 64 + 2 * c);
            float2 u = *(const float2*)(smem + OFF_U2S + (o0 + WU - j) * 272 + c * 8);
            hre = fmaf(lp.x, u.x, hre); hre = fmaf(-lp.y, u.y, hre);
            him = fmaf(lp.x, u.y, him); him = fmaf(lp.y, u.x, him);
        }
        *(unsigned*)(smem + OFF_BIMG + o0 * 208 + c * 4) = (bf16r(him) << 16) | bf16r(hre);
        for (int s = 1; s < 8; ++s) {
            float2 u = *(const float2*)(smem + OFF_U2S + (o0 + WU + s) * 272 + c * 8);
            float nre = lr * hre - li * him + g * u.x;
            float nim = lr * him + li * hre + g * u.y;
            hre = nre; him = nim;
            *(unsigned*)(smem + OFF_BIMG + (o0 + s) * 208 + c * 4) = (bf16r(him) << 16) | bf16r(hre);
        }
    }
    __syncthreads();

    // GEMM4: out rows = wid*64..wid*64+63 ; A (Wcat hi/lo) from global (L2)
    f32x4 acc[4][4];
    #pragma unroll
    for (int mi = 0; mi < 4; ++mi)
        #pragma unroll
        for (int n = 0; n < 4; ++n) acc[mi][n] = f32x4{0.f, 0.f, 0.f, 0.f};

    #pragma unroll 1
    for (int ks = 0; ks < 3; ++ks) {
        bf16x8 ah[4], al[4];
        #pragma unroll
        for (int mi = 0; mi < 4; ++mi) {
            int row = (wid * 4 + mi) * 16 + l15;
            ah[mi] = *(const bf16x8*)(whi + row * 96 + ks * 32 + lq * 8);
            al[mi] = *(const bf16x8*)(wlo + row * 96 + ks * 32 + lq * 8);
        }
        #pragma unroll
        for (int n = 0; n < 4; ++n) {
            bf16x8 bb = *(const bf16x8*)(smem + OFF_BIMG + (n * 16 + l15) * 208 + ks * 64 + lq * 16);
            #pragma unroll
            for (int mi = 0; mi < 4; ++mi) {
                acc[mi][n] = __builtin_amdgcn_mfma_f32_16x16x32_bf16(ah[mi], bb, acc[mi][n], 0, 0, 0);
                acc[mi][n] = __builtin_amdgcn_mfma_f32_16x16x32_bf16(al[mi], bb, acc[mi][n], 0, 0, 0);
            }
        }
    }
    #pragma unroll
    for (int mi = 0; mi < 4; ++mi) {
        int row0 = (wid * 4 + mi) * 16 + lq * 4;
        #pragma unroll
        for (int n = 0; n < 4; ++n) {
            int t = t0 + n * 16 + l15;
            #pragma unroll
            for (int j = 0; j < 4; ++j)
                out[(size_t)(row0 + j) * LFRAMES + t] = acc[mi][n][j];
        }
    }
}

extern "C" void kernel_launch(void* const* d_in, const int* in_sizes, int n_in,
                              void* d_out, int out_size, void* d_ws, size_t ws_size,
                              hipStream_t stream)
{
    const float* x     = (const float*)d_in[0];
    const float* b1r   = (const float*)d_in[1];
    const float* b1i   = (const float*)d_in[2];
    const float* nu1   = (const float*)d_in[3];
    const float* th1   = (const float*)d_in[4];
    const float* c1r   = (const float*)d_in[5];
    const float* c1i   = (const float*)d_in[6];
    const float* d1    = (const float*)d_in[7];
    const float* mlp_w = (const float*)d_in[8];
    const float* mlp_b = (const float*)d_in[9];
    const float* b2r   = (const float*)d_in[10];
    const float* b2i   = (const float*)d_in[11];
    const float* nu2   = (const float*)d_in[12];
    const float* th2   = (const float*)d_in[13];
    const float* c2r   = (const float*)d_in[14];
    const float* c2i   = (const float*)d_in[15];
    const float* d2    = (const float*)d_in[16];
    float* out = (float*)d_out;

    // workspace layout (21.07 MB total)
    unsigned short* y2ws = (unsigned short*)d_ws;                         // L*32 bf16 = 4,194,304 B
    float* u2ws          = (float*)((char*)d_ws + 4194304);               // L*64 f32  = 16,777,216 B
    unsigned short* whi  = (unsigned short*)((char*)d_ws + 20971520);     // 49,152 B
    unsigned short* wlo  = (unsigned short*)((char*)d_ws + 21020672);     // 49,152 B

    prep_wcat<<<dim3((O2 * 96 + 255) / 256), dim3(256), 0, stream>>>(c2r, c2i, d2, whi, wlo);

    lru_stage1<<<dim3(LFRAMES / S1_FO), dim3(512), 0, stream>>>(
        x, b1r, b1i, nu1, th1, c1r, c1i, d1, mlp_w, mlp_b, b2r, b2i, y2ws, u2ws);

    lru_stage2<<<dim3(LFRAMES / S2_FO), dim3(256), 0, stream>>>(
        u2ws, y2ws, nu2, th2, whi, wlo, out);
}

// Round 4
// 47.513 us; speedup vs baseline: 9.3504x; 1.2592x over previous
//
#include <hip/hip_runtime.h>

#define WINDOW 128
#define H 32
#define O2 256
#define LFRAMES 65536
#define WU 32
#define FO_BLK 256     // output frames per block
#define FM 288         // mid (y-chain) frames per block
#define FS 320         // staged x frames per block

using bf16x8 = __attribute__((ext_vector_type(8))) short;
using f32x4  = __attribute__((ext_vector_type(4))) float;
using u16x4  = __attribute__((ext_vector_type(4))) unsigned short;

__device__ __forceinline__ unsigned bf16r(float v) {   // RTNE float->bf16 bits
    unsigned u = __builtin_bit_cast(unsigned, v);
    return (u + 0x7FFFu + ((u >> 16) & 1u)) >> 16;
}
__device__ __forceinline__ float bf2f(unsigned s) {
    return __builtin_bit_cast(float, s << 16);
}
__device__ __forceinline__ float selu_f(float x) {
    const float scale = 1.0507009873554805f;
    const float alpha = 1.6732632423543772f;
    return scale * (x > 0.0f ? x : alpha * (expf(x) - 1.0f));
}
__device__ __forceinline__ bf16x8 cvt8(float4 a, float4 b) {
    bf16x8 r;
    r[0] = (short)bf16r(a.x); r[1] = (short)bf16r(a.y);
    r[2] = (short)bf16r(a.z); r[3] = (short)bf16r(a.w);
    r[4] = (short)bf16r(b.x); r[5] = (short)bf16r(b.y);
    r[6] = (short)bf16r(b.z); r[7] = (short)bf16r(b.w);
    return r;
}

// ---------------- fused-kernel LDS byte offsets (total 159872 <= 160KiB) ----
#define OFF_LAM1   0        // [32 taps][64 f32]                       (8192)
#define OFF_LAM2   8192     //                                         (8192)
#define OFF_C1HI   16384    // [32][72] bf16, pitch 144B               (4608)
#define OFF_C1LO   20992
#define OFF_MWHI   25600    // [32][40] bf16, pitch 80B                (2560)
#define OFF_MWLO   28160
#define OFF_B2HI   30720    // [64][40] bf16, pitch 80B                (5120)
#define OFF_B2LO   35840
#define OFF_BIAS   40960    // [32] f32                                (128)
#define OFF_P      41088    // u1 [320][68]bf16 p136  | y1s [288][40]bf16 p80 | u2s [288][68]bf16 p136
#define OFF_D      84608    // d1x [288][40]bf16 p80  | y2l [288][40]bf16 p80
#define OFF_W      107648   // W1HI [96][136]bf16 p272 (26112) + W1LO  | h1 [288][72]bf16 p144 | h2 [256][72]bf16 p144
#define OFF_W1LO   133760
#define S_LDS      159872

// ---------------------------------------------------------------------------
// prep: wcat (256 x 96) bf16 hi/lo. k<64: even->c2r, odd->-c2i; k>=64: d2.
// ---------------------------------------------------------------------------
__global__ void prep_wcat(const float* __restrict__ c2r, const float* __restrict__ c2i,
                          const float* __restrict__ d2,
                          unsigned short* __restrict__ whi, unsigned short* __restrict__ wlo)
{
    int idx = blockIdx.x * 256 + threadIdx.x;
    if (idx >= O2 * 96) return;
    int row = idx / 96, k = idx - row * 96;
    float v;
    if (k < 64) v = (k & 1) ? -c2i[row * H + (k >> 1)] : c2r[row * H + (k >> 1)];
    else        v = d2[row * H + (k - 64)];
    unsigned h = bf16r(v);
    whi[idx] = (unsigned short)h;
    wlo[idx] = (unsigned short)bf16r(v - bf2f(h));
}

// ---------------------------------------------------------------------------
// Fused kernel: x -> out, everything in LDS. 256 blocks x 512 threads.
// ---------------------------------------------------------------------------
__global__ __launch_bounds__(512, 1)
void lru_fused(const float* __restrict__ x,
               const float* __restrict__ b1r, const float* __restrict__ b1i,
               const float* __restrict__ nu1, const float* __restrict__ th1,
               const float* __restrict__ c1r, const float* __restrict__ c1i,
               const float* __restrict__ d1,
               const float* __restrict__ mlp_w, const float* __restrict__ mlp_b,
               const float* __restrict__ b2r, const float* __restrict__ b2i,
               const float* __restrict__ nu2, const float* __restrict__ th2,
               const unsigned short* __restrict__ whi, const unsigned short* __restrict__ wlo,
               float* __restrict__ out)
{
    __shared__ __align__(16) char smem[S_LDS];
    const int tid = threadIdx.x;
    const int t0 = blockIdx.x * FO_BLK;
    const int frame0 = t0 - 64;              // global frame of staged idx 0
    const int w = tid >> 6, l = tid & 63, l15 = l & 15, lq = l >> 4;

    // ================= phase 0: weights -> LDS, lambda tables =================
    if (tid < H) {
        // lam1 table: gamma1 * lam1^j
        {
            float enu = expf(nu1[tid]);
            float mag = expf(-enu);
            float ang = expf(th1[tid]);
            float lr = mag * cosf(ang), li = mag * sinf(ang);
            float g = sqrtf(fmaxf(1.0f - mag * mag, 0.0f));
            float pr = g, pi = 0.0f;
            float* lam = (float*)(smem + OFF_LAM1);
            for (int j = 0; j < WU; ++j) {
                lam[j * 64 + 2 * tid] = pr;
                lam[j * 64 + 2 * tid + 1] = pi;
                float npr = pr * lr - pi * li, npi = pr * li + pi * lr;
                pr = npr; pi = npi;
            }
        }
        // lam2 table
        {
            float enu = expf(nu2[tid]);
            float mag = expf(-enu);
            float ang = expf(th2[tid]);
            float lr = mag * cosf(ang), li = mag * sinf(ang);
            float g = sqrtf(fmaxf(1.0f - mag * mag, 0.0f));
            float pr = g, pi = 0.0f;
            float* lam = (float*)(smem + OFF_LAM2);
            for (int j = 0; j < WU; ++j) {
                lam[j * 64 + 2 * tid] = pr;
                lam[j * 64 + 2 * tid + 1] = pi;
                float npr = pr * lr - pi * li, npi = pr * li + pi * lr;
                pr = npr; pi = npi;
            }
        }
        ((float*)(smem + OFF_BIAS))[tid] = mlp_b[tid];
    }
    // W1: rows 0..63 interleaved (2c=b1r[c], 2c+1=b1i[c]), rows 64..95 = d1
    {
        unsigned short* hi = (unsigned short*)(smem + OFF_W);
        unsigned short* lo = (unsigned short*)(smem + OFF_W1LO);
        #pragma unroll
        for (int p = 0; p < 24; ++p) {
            int idx = tid + 512 * p;
            int row = idx >> 7, k = idx & 127;
            float v;
            if (row < 64) v = (row & 1) ? b1i[(row >> 1) * WINDOW + k] : b1r[(row >> 1) * WINDOW + k];
            else          v = d1[(row - 64) * WINDOW + k];
            unsigned h = bf16r(v);
            hi[row * 136 + k] = (unsigned short)h;
            lo[row * 136 + k] = (unsigned short)bf16r(v - bf2f(h));
        }
    }
    // C1cat: [32][64], k even -> c1r, k odd -> -c1i
    {
        unsigned short* hi = (unsigned short*)(smem + OFF_C1HI);
        unsigned short* lo = (unsigned short*)(smem + OFF_C1LO);
        #pragma unroll
        for (int p = 0; p < 4; ++p) {
            int idx = tid + 512 * p;
            int row = idx >> 6, k = idx & 63;
            float v = (k & 1) ? -c1i[row * H + (k >> 1)] : c1r[row * H + (k >> 1)];
            unsigned h = bf16r(v);
            hi[row * 72 + k] = (unsigned short)h;
            lo[row * 72 + k] = (unsigned short)bf16r(v - bf2f(h));
        }
    }
    // mlpw^T
    {
        unsigned short* hi = (unsigned short*)(smem + OFF_MWHI);
        unsigned short* lo = (unsigned short*)(smem + OFF_MWLO);
        #pragma unroll
        for (int p = 0; p < 2; ++p) {
            int idx = tid + 512 * p;
            int row = idx >> 5, k = idx & 31;
            float v = mlp_w[k * H + row];
            unsigned h = bf16r(v);
            hi[row * 40 + k] = (unsigned short)h;
            lo[row * 40 + k] = (unsigned short)bf16r(v - bf2f(h));
        }
    }
    // b2cat: rows interleaved (2c=b2r[c], 2c+1=b2i[c]), K=32
    {
        unsigned short* hi = (unsigned short*)(smem + OFF_B2HI);
        unsigned short* lo = (unsigned short*)(smem + OFF_B2LO);
        #pragma unroll
        for (int p = 0; p < 4; ++p) {
            int idx = tid + 512 * p;
            int row = idx >> 5, k = idx & 31;
            float v = (row & 1) ? b2i[(row >> 1) * H + k] : b2r[(row >> 1) * H + k];
            unsigned h = bf16r(v);
            hi[row * 40 + k] = (unsigned short)h;
            lo[row * 40 + k] = (unsigned short)bf16r(v - bf2f(h));
        }
    }
    __syncthreads();

    // ================= GEMM1: U1 (96 x 320) = W1 @ X =========================
    // 20 N-tiles; waves 0-3 own tiles {w, w+8, w+16}, waves 4-7 own {w, w+8}.
    {
        f32x4 acc1[3][6];
        #pragma unroll
        for (int ni = 0; ni < 3; ++ni)
            #pragma unroll
            for (int m = 0; m < 6; ++m) acc1[ni][m] = f32x4{0.f, 0.f, 0.f, 0.f};

        #pragma unroll 1
        for (int ks = 0; ks < 4; ++ks) {
            bf16x8 ah[6], al[6];
            #pragma unroll
            for (int m = 0; m < 6; ++m) {
                int ro = (m * 16 + l15) * 272 + ks * 64 + lq * 16;
                ah[m] = *(const bf16x8*)(smem + OFF_W + ro);
                al[m] = *(const bf16x8*)(smem + OFF_W1LO + ro);
            }
            #pragma unroll
            for (int ni = 0; ni < 3; ++ni) {
                int nt = w + ni * 8;
                if (nt < 20) {
                    int gf = frame0 + nt * 16 + l15;
                    float4 xa{}, xb{};
                    if (gf >= 0) {
                        const float4* xp = (const float4*)(x + (size_t)gf * WINDOW + ks * 32 + lq * 8);
                        xa = xp[0]; xb = xp[1];
                    }
                    bf16x8 b = cvt8(xa, xb);
                    #pragma unroll
                    for (int m = 0; m < 6; ++m) {
                        acc1[ni][m] = __builtin_amdgcn_mfma_f32_16x16x32_bf16(ah[m], b, acc1[ni][m], 0, 0, 0);
                        acc1[ni][m] = __builtin_amdgcn_mfma_f32_16x16x32_bf16(al[m], b, acc1[ni][m], 0, 0, 0);
                    }
                }
            }
        }
        // epilogue: rows 0..63 -> P (u1 bf16, all 320 frames); 64..95 -> d1x bf16 (288 mid)
        #pragma unroll
        for (int ni = 0; ni < 3; ++ni) {
            int nt = w + ni * 8;
            if (nt < 20) {
                int fs = nt * 16 + l15;
                #pragma unroll
                for (int m = 0; m < 4; ++m) {
                    u16x4 pk;
                    #pragma unroll
                    for (int j = 0; j < 4; ++j) pk[j] = (unsigned short)bf16r(acc1[ni][m][j]);
                    *(u16x4*)(smem + OFF_P + fs * 136 + (m * 16 + lq * 4) * 2) = pk;
                }
                if (fs >= 32) {
                    int fm = fs - 32;
                    #pragma unroll
                    for (int m = 4; m < 6; ++m) {
                        u16x4 pk;
                        #pragma unroll
                        for (int j = 0; j < 4; ++j) pk[j] = (unsigned short)bf16r(acc1[ni][m][j]);
                        *(u16x4*)(smem + OFF_D + fm * 80 + ((m - 4) * 16 + lq * 4) * 2) = pk;
                    }
                }
            }
        }
    }
    __syncthreads();

    // ================= conv1: 288 mid states -> h1 (bf16) ====================
    {
        int c = tid & 31, g = tid >> 5;          // 16 groups x 18 frames
        float enu = expf(nu1[c]);
        float mag = expf(-enu);
        float ang = expf(th1[c]);
        float lr = mag * cosf(ang), li = mag * sinf(ang);
        float gam = sqrtf(fmaxf(1.0f - mag * mag, 0.0f));
        const float* lam = (const float*)(smem + OFF_LAM1);
        int fmb = g * 18;
        float hre = 0.f, him = 0.f;
        for (int j = 0; j < WU; ++j) {
            float2 lp = *(const float2*)(lam + j * 64 + 2 * c);
            unsigned uw = *(const unsigned*)(smem + OFF_P + (fmb + 32 - j) * 136 + c * 4);
            float ur = bf2f(uw & 0xFFFFu), ui = bf2f(uw >> 16);
            hre = fmaf(lp.x, ur, hre); hre = fmaf(-lp.y, ui, hre);
            him = fmaf(lp.x, ui, him); him = fmaf(lp.y, ur, him);
        }
        *(unsigned*)(smem + OFF_W + fmb * 144 + c * 4) = (bf16r(him) << 16) | bf16r(hre);
        for (int s = 1; s < 18; ++s) {
            unsigned uw = *(const unsigned*)(smem + OFF_P + (fmb + 32 + s) * 136 + c * 4);
            float ur = bf2f(uw & 0xFFFFu), ui = bf2f(uw >> 16);
            float nre = lr * hre - li * him + gam * ur;
            float nim = lr * him + li * hre + gam * ui;
            hre = nre; him = nim;
            *(unsigned*)(smem + OFF_W + (fmb + s) * 144 + c * 4) = (bf16r(him) << 16) | bf16r(hre);
        }
    }
    __syncthreads();

    // ================= GEMM2: y1 = C1cat @ h1 + d1x ; selu -> y1s ============
    #pragma unroll 1
    for (int ci = w; ci < 36; ci += 8) {
        int n = ci >> 1, m = ci & 1;
        int fcol = n * 16 + l15;
        u16x4 dk = *(const u16x4*)(smem + OFF_D + fcol * 80 + (m * 16 + lq * 4) * 2);
        f32x4 c;
        #pragma unroll
        for (int j = 0; j < 4; ++j) c[j] = bf2f(dk[j]);
        #pragma unroll
        for (int ks = 0; ks < 2; ++ks) {
            int ao = (m * 16 + l15) * 144 + ks * 64 + lq * 16;
            bf16x8 ah = *(const bf16x8*)(smem + OFF_C1HI + ao);
            bf16x8 al = *(const bf16x8*)(smem + OFF_C1LO + ao);
            bf16x8 bb = *(const bf16x8*)(smem + OFF_W + fcol * 144 + ks * 64 + lq * 16);
            c = __builtin_amdgcn_mfma_f32_16x16x32_bf16(ah, bb, c, 0, 0, 0);
            c = __builtin_amdgcn_mfma_f32_16x16x32_bf16(al, bb, c, 0, 0, 0);
        }
        u16x4 pk;
        #pragma unroll
        for (int j = 0; j < 4; ++j) pk[j] = (unsigned short)bf16r(selu_f(c[j]));
        *(u16x4*)(smem + OFF_P + fcol * 80 + (m * 16 + lq * 4) * 2) = pk;
    }
    __syncthreads();

    // ================= MLP: y2 = mlpw^T @ y1s + bias ; selu -> y2l ===========
    #pragma unroll 1
    for (int ci = w; ci < 36; ci += 8) {
        int n = ci >> 1, m = ci & 1;
        int fcol = n * 16 + l15;
        f32x4 c = *(const f32x4*)(smem + OFF_BIAS + (m * 16 + lq * 4) * 4);
        {
            int ao = (m * 16 + l15) * 80 + lq * 16;
            bf16x8 ah = *(const bf16x8*)(smem + OFF_MWHI + ao);
            bf16x8 al = *(const bf16x8*)(smem + OFF_MWLO + ao);
            bf16x8 bb = *(const bf16x8*)(smem + OFF_P + fcol * 80 + lq * 16);
            c = __builtin_amdgcn_mfma_f32_16x16x32_bf16(ah, bb, c, 0, 0, 0);
            c = __builtin_amdgcn_mfma_f32_16x16x32_bf16(al, bb, c, 0, 0, 0);
        }
        u16x4 pk;
        #pragma unroll
        for (int j = 0; j < 4; ++j) pk[j] = (unsigned short)bf16r(selu_f(c[j]));
        *(u16x4*)(smem + OFF_D + fcol * 80 + (m * 16 + lq * 4) * 2) = pk;
    }
    __syncthreads();

    // ================= GEMM3: u2 = b2cat @ y2l -> u2s (bf16) =================
    #pragma unroll 1
    for (int ci = w; ci < 72; ci += 8) {
        int n = ci >> 2, m = ci & 3;
        int fcol = n * 16 + l15;
        f32x4 c = f32x4{0.f, 0.f, 0.f, 0.f};
        {
            int ao = (m * 16 + l15) * 80 + lq * 16;
            bf16x8 ah = *(const bf16x8*)(smem + OFF_B2HI + ao);
            bf16x8 al = *(const bf16x8*)(smem + OFF_B2LO + ao);
            bf16x8 bb = *(const bf16x8*)(smem + OFF_D + fcol * 80 + lq * 16);
            c = __builtin_amdgcn_mfma_f32_16x16x32_bf16(ah, bb, c, 0, 0, 0);
            c = __builtin_amdgcn_mfma_f32_16x16x32_bf16(al, bb, c, 0, 0, 0);
        }
        // negative global frames must contribute zero u2 (bias-independent correctness)
        if (t0 - 32 + fcol < 0) c = f32x4{0.f, 0.f, 0.f, 0.f};
        u16x4 pk;
        #pragma unroll
        for (int j = 0; j < 4; ++j) pk[j] = (unsigned short)bf16r(c[j]);
        *(u16x4*)(smem + OFF_P + fcol * 136 + (m * 16 + lq * 4) * 2) = pk;
    }
    __syncthreads();

    // ================= conv2: 256 out states -> h2 (bf16) ====================
    {
        int c = tid & 31, g = tid >> 5;          // 16 groups x 16 frames
        float enu = expf(nu2[c]);
        float mag = expf(-enu);
        float ang = expf(th2[c]);
        float lr = mag * cosf(ang), li = mag * sinf(ang);
        float gam = sqrtf(fmaxf(1.0f - mag * mag, 0.0f));
        const float* lam = (const float*)(smem + OFF_LAM2);
        int fob = g * 16;
        float hre = 0.f, him = 0.f;
        for (int j = 0; j < WU; ++j) {
            float2 lp = *(const float2*)(lam + j * 64 + 2 * c);
            unsigned uw = *(const unsigned*)(smem + OFF_P + (fob + 32 - j) * 136 + c * 4);
            float ur = bf2f(uw & 0xFFFFu), ui = bf2f(uw >> 16);
            hre = fmaf(lp.x, ur, hre); hre = fmaf(-lp.y, ui, hre);
            him = fmaf(lp.x, ui, him); him = fmaf(lp.y, ur, him);
        }
        *(unsigned*)(smem + OFF_W + fob * 144 + c * 4) = (bf16r(him) << 16) | bf16r(hre);
        for (int s = 1; s < 16; ++s) {
            unsigned uw = *(const unsigned*)(smem + OFF_P + (fob + 32 + s) * 136 + c * 4);
            float ur = bf2f(uw & 0xFFFFu), ui = bf2f(uw >> 16);
            float nre = lr * hre - li * him + gam * ur;
            float nim = lr * him + li * hre + gam * ui;
            hre = nre; him = nim;
            *(unsigned*)(smem + OFF_W + (fob + s) * 144 + c * 4) = (bf16r(him) << 16) | bf16r(hre);
        }
    }
    __syncthreads();

    // ================= GEMM4: out = wcat @ [h2 ; y2] ==========================
    // wave w owns M-tiles {2w, 2w+1}; 16 N-tiles of 16 frames.
    {
        f32x4 acc[2][16];
        #pragma unroll
        for (int mi = 0; mi < 2; ++mi)
            #pragma unroll
            for (int n = 0; n < 16; ++n) acc[mi][n] = f32x4{0.f, 0.f, 0.f, 0.f};

        #pragma unroll 1
        for (int ks = 0; ks < 3; ++ks) {
            bf16x8 ah[2], al[2];
            #pragma unroll
            for (int mi = 0; mi < 2; ++mi) {
                int row = (2 * w + mi) * 16 + l15;
                ah[mi] = *(const bf16x8*)(whi + row * 96 + ks * 32 + lq * 8);
                al[mi] = *(const bf16x8*)(wlo + row * 96 + ks * 32 + lq * 8);
            }
            #pragma unroll
            for (int n = 0; n < 16; ++n) {
                int fcol = n * 16 + l15;
                bf16x8 bb;
                if (ks < 2) bb = *(const bf16x8*)(smem + OFF_W + fcol * 144 + ks * 64 + lq * 16);
                else        bb = *(const bf16x8*)(smem + OFF_D + (fcol + 32) * 80 + lq * 16);
                #pragma unroll
                for (int mi = 0; mi < 2; ++mi) {
                    acc[mi][n] = __builtin_amdgcn_mfma_f32_16x16x32_bf16(ah[mi], bb, acc[mi][n], 0, 0, 0);
                    acc[mi][n] = __builtin_amdgcn_mfma_f32_16x16x32_bf16(al[mi], bb, acc[mi][n], 0, 0, 0);
                }
            }
        }
        #pragma unroll
        for (int mi = 0; mi < 2; ++mi) {
            int row0 = (2 * w + mi) * 16 + lq * 4;
            #pragma unroll
            for (int n = 0; n < 16; ++n) {
                int t = t0 + n * 16 + l15;
                #pragma unroll
                for (int j = 0; j < 4; ++j)
                    out[(size_t)(row0 + j) * LFRAMES + t] = acc[mi][n][j];
            }
        }
    }
}

extern "C" void kernel_launch(void* const* d_in, const int* in_sizes, int n_in,
                              void* d_out, int out_size, void* d_ws, size_t ws_size,
                              hipStream_t stream)
{
    const float* x     = (const float*)d_in[0];
    const float* b1r   = (const float*)d_in[1];
    const float* b1i   = (const float*)d_in[2];
    const float* nu1   = (const float*)d_in[3];
    const float* th1   = (const float*)d_in[4];
    const float* c1r   = (const float*)d_in[5];
    const float* c1i   = (const float*)d_in[6];
    const float* d1    = (const float*)d_in[7];
    const float* mlp_w = (const float*)d_in[8];
    const float* mlp_b = (const float*)d_in[9];
    const float* b2r   = (const float*)d_in[10];
    const float* b2i   = (const float*)d_in[11];
    const float* nu2   = (const float*)d_in[12];
    const float* th2   = (const float*)d_in[13];
    const float* c2r   = (const float*)d_in[14];
    const float* c2i   = (const float*)d_in[15];
    const float* d2    = (const float*)d_in[16];
    float* out = (float*)d_out;

    unsigned short* whi = (unsigned short*)d_ws;                      // 49,152 B
    unsigned short* wlo = (unsigned short*)((char*)d_ws + 49152);     // 49,152 B

    prep_wcat<<<dim3((O2 * 96 + 255) / 256), dim3(256), 0, stream>>>(c2r, c2i, d2, whi, wlo);

    lru_fused<<<dim3(LFRAMES / FO_BLK), dim3(512), 0, stream>>>(
        x, b1r, b1i, nu1, th1, c1r, c1i, d1, mlp_w, mlp_b,
        b2r, b2i, nu2, th2, whi, wlo, out);
}